// Round 1
// baseline (629.191 us; speedup 1.0000x reference)
//
#include <hip/hip_runtime.h>

// Problem constants (from reference): F0=64, F1=128, F2=64.

__global__ void deg_kernel(const int* __restrict__ src, const int* __restrict__ dst,
                           float* __restrict__ deg_out, float* __restrict__ deg_in,
                           int n_edges) {
    int e = blockIdx.x * blockDim.x + threadIdx.x;
    if (e < n_edges) {
        atomicAdd(&deg_out[src[e]], 1.0f);
        atomicAdd(&deg_in[dst[e]], 1.0f);
    }
}

// In-place deg -> clip(deg,1)^-0.5 over a contiguous span (covers both arrays).
__global__ void norm_kernel(float* __restrict__ deg, int n) {
    int i = blockIdx.x * blockDim.x + threadIdx.x;
    if (i < n) {
        float d = deg[i];
        d = d < 1.0f ? 1.0f : d;
        deg[i] = 1.0f / sqrtf(d);
    }
}

// x = h * norm_src[node], vectorized: 16 float4 per node (F=64)
__global__ void scale_kernel(const float4* __restrict__ h4, const float* __restrict__ norm,
                             float4* __restrict__ x4, int n4) {
    int idx = blockIdx.x * blockDim.x + threadIdx.x;
    if (idx < n4) {
        int node = idx >> 4;
        float s = norm[node];
        float4 v = h4[idx];
        v.x *= s; v.y *= s; v.z *= s; v.w *= s;
        x4[idx] = v;
    }
}

// 64 lanes per edge: lane f does agg[dst*64+f] += x[src*64+f]
__global__ void scatter64(const float* __restrict__ x, const int* __restrict__ src,
                          const int* __restrict__ dst, float* __restrict__ agg,
                          int n_edges) {
    int g = blockIdx.x * blockDim.x + threadIdx.x;
    int e = g >> 6;
    int f = g & 63;
    if (e < n_edges) {
        int s = src[e];
        int d = dst[e];
        atomicAdd(&agg[d * 64 + f], x[s * 64 + f]);
    }
}

// Fused per-node: t = agg1[i]*norm_in[i]; h1 = relu(t@W1 + b1);
//                 y2 = (h1*norm_out[i]) @ W2
// 256 threads = 2 groups of 128 (one node each). W1 (64x128) + W2 (128x64) in LDS.
__global__ __launch_bounds__(256) void fused_gemm(
        const float* __restrict__ agg1, const float* __restrict__ norm_in,
        const float* __restrict__ norm_out,
        const float* __restrict__ W1, const float* __restrict__ b1,
        const float* __restrict__ W2, float* __restrict__ y2, int n_nodes) {
    __shared__ float W1s[64 * 128];
    __shared__ float W2s[128 * 64];
    __shared__ float b1s[128];
    __shared__ float tt[2][64];
    __shared__ float hs[2][128];

    for (int idx = threadIdx.x; idx < 64 * 128; idx += 256) {
        W1s[idx] = W1[idx];
        W2s[idx] = W2[idx];
    }
    if (threadIdx.x < 128) b1s[threadIdx.x] = b1[threadIdx.x];
    __syncthreads();

    const int g  = threadIdx.x >> 7;   // group 0/1
    const int tj = threadIdx.x & 127;  // 0..127 within group

    for (int i0 = blockIdx.x * 2; i0 < n_nodes; i0 += gridDim.x * 2) {
        int i = i0 + g;
        bool valid = (i < n_nodes);
        if (valid && tj < 64) tt[g][tj] = agg1[i * 64 + tj] * norm_in[i];
        __syncthreads();
        if (valid) {
            float acc = b1s[tj];
            #pragma unroll
            for (int k = 0; k < 64; ++k) acc += tt[g][k] * W1s[k * 128 + tj];
            acc = acc > 0.0f ? acc : 0.0f;          // relu
            hs[g][tj] = acc * norm_out[i];          // fold norm_src for layer 2
        }
        __syncthreads();
        if (valid && tj < 64) {
            float acc = 0.0f;
            #pragma unroll
            for (int j = 0; j < 128; ++j) acc += hs[g][j] * W2s[j * 64 + tj];
            y2[i * 64 + tj] = acc;
        }
        __syncthreads();  // protect tt/hs before next iteration
    }
}

// out = agg2 * norm_in[node] + b2[feat]
__global__ void final_kernel(const float* __restrict__ agg2, const float* __restrict__ norm_in,
                             const float* __restrict__ b2, float* __restrict__ out, int total) {
    int idx = blockIdx.x * blockDim.x + threadIdx.x;
    if (idx < total) {
        int i = idx >> 6;
        int j = idx & 63;
        out[idx] = agg2[idx] * norm_in[i] + b2[j];
    }
}

extern "C" void kernel_launch(void* const* d_in, const int* in_sizes, int n_in,
                              void* d_out, int out_size, void* d_ws, size_t ws_size,
                              hipStream_t stream) {
    const float* h   = (const float*)d_in[0];
    const int*   src = (const int*)d_in[1];
    const int*   dst = (const int*)d_in[2];
    const float* W1  = (const float*)d_in[3];
    const float* b1  = (const float*)d_in[4];
    const float* W2  = (const float*)d_in[5];
    const float* b2  = (const float*)d_in[6];
    float* out = (float*)d_out;

    const int n_nodes = in_sizes[0] / 64;
    const int n_edges = in_sizes[1];

    float* ws      = (float*)d_ws;
    float* deg_out = ws;                         // [n]  -> becomes norm_src
    float* deg_in  = ws + n_nodes;               // [n]  -> becomes norm_dst
    float* x       = ws + 2 * (size_t)n_nodes;   // [n,64]
    float* agg1    = x    + (size_t)n_nodes * 64; // [n,64]
    float* y2      = agg1 + (size_t)n_nodes * 64; // [n,64]
    float* agg2    = y2   + (size_t)n_nodes * 64; // [n,64]

    // Zero the accumulation buffers (ws is re-poisoned to 0xAA before each call)
    hipMemsetAsync(deg_out, 0, 2 * (size_t)n_nodes * sizeof(float), stream);
    hipMemsetAsync(agg1, 0, (size_t)n_nodes * 64 * sizeof(float), stream);
    hipMemsetAsync(agg2, 0, (size_t)n_nodes * 64 * sizeof(float), stream);

    deg_kernel<<<(n_edges + 255) / 256, 256, 0, stream>>>(src, dst, deg_out, deg_in, n_edges);
    norm_kernel<<<(2 * n_nodes + 255) / 256, 256, 0, stream>>>(deg_out, 2 * n_nodes);

    int n4 = n_nodes * 16;
    scale_kernel<<<(n4 + 255) / 256, 256, 0, stream>>>((const float4*)h, deg_out, (float4*)x, n4);

    long long sc_threads = (long long)n_edges * 64;
    int sc_blocks = (int)((sc_threads + 255) / 256);
    scatter64<<<sc_blocks, 256, 0, stream>>>(x, src, dst, agg1, n_edges);

    fused_gemm<<<1024, 256, 0, stream>>>(agg1, deg_in, deg_out, W1, b1, W2, y2, n_nodes);

    scatter64<<<sc_blocks, 256, 0, stream>>>(y2, src, dst, agg2, n_edges);

    final_kernel<<<(n_nodes * 64 + 255) / 256, 256, 0, stream>>>(agg2, deg_in, b2, out, n_nodes * 64);
}

// Round 2
// 438.757 us; speedup vs baseline: 1.4340x; 1.4340x over previous
//
#include <hip/hip_runtime.h>

// F0=64, F1=128, F2=64. Strategy: counting-sort edges by dst -> CSR, then
// gather-based segment reduction (no feature atomics).

__global__ void count_kernel(const int* __restrict__ src, const int* __restrict__ dst,
                             int* __restrict__ cnt_out, int* __restrict__ cnt_in,
                             int n_edges) {
    int e = blockIdx.x * blockDim.x + threadIdx.x;
    if (e < n_edges) {
        atomicAdd(&cnt_out[src[e]], 1);
        atomicAdd(&cnt_in[dst[e]], 1);
    }
}

__global__ void norm_kernel(const int* __restrict__ cnt_out, const int* __restrict__ cnt_in,
                            float* __restrict__ norm_src, float* __restrict__ norm_dst, int n) {
    int i = blockIdx.x * blockDim.x + threadIdx.x;
    if (i < n) {
        int co = cnt_out[i]; if (co < 1) co = 1;
        int ci = cnt_in[i];  if (ci < 1) ci = 1;
        norm_src[i] = 1.0f / sqrtf((float)co);
        norm_dst[i] = 1.0f / sqrtf((float)ci);
    }
}

// Single-block exclusive scan of cnt[0..n) -> offs[0..n], also copied to cursor.
__global__ __launch_bounds__(1024) void scan_kernel(const int* __restrict__ cnt,
                                                    int* __restrict__ offs,
                                                    int* __restrict__ cursor, int n) {
    __shared__ int wsum[16];
    const int lane = threadIdx.x & 63;
    const int wid  = threadIdx.x >> 6;
    int carry = 0;  // uniform across threads
    for (int base = 0; base < n; base += 1024) {
        int i = base + (int)threadIdx.x;
        int v = (i < n) ? cnt[i] : 0;
        int incl = v;
        #pragma unroll
        for (int d = 1; d < 64; d <<= 1) {
            int t = __shfl_up(incl, d, 64);
            if (lane >= d) incl += t;
        }
        if (lane == 63) wsum[wid] = incl;
        __syncthreads();
        if (wid == 0) {
            int w = (lane < 16) ? wsum[lane] : 0;
            #pragma unroll
            for (int d = 1; d < 16; d <<= 1) {
                int t = __shfl_up(w, d, 64);
                if (lane >= d) w += t;
            }
            if (lane < 16) wsum[lane] = w;
        }
        __syncthreads();
        int wexcl = (wid == 0) ? 0 : wsum[wid - 1];
        int excl = carry + wexcl + (incl - v);
        if (i < n) { offs[i] = excl; cursor[i] = excl; }
        int total = wsum[15];
        __syncthreads();  // wsum reused next iteration
        carry += total;
    }
    if (threadIdx.x == 0) offs[n] = carry;
}

__global__ void place_kernel(const int* __restrict__ src, const int* __restrict__ dst,
                             int* __restrict__ cursor, int* __restrict__ src_sorted,
                             int n_edges) {
    int e = blockIdx.x * blockDim.x + threadIdx.x;
    if (e < n_edges) {
        int p = atomicAdd(&cursor[dst[e]], 1);
        src_sorted[p] = src[e];
    }
}

// x = h * norm_src[node], 16 float4 per node
__global__ void scale_kernel(const float4* __restrict__ h4, const float* __restrict__ norm,
                             float4* __restrict__ x4, int n4) {
    int idx = blockIdx.x * blockDim.x + threadIdx.x;
    if (idx < n4) {
        float s = norm[idx >> 4];
        float4 v = h4[idx];
        v.x *= s; v.y *= s; v.z *= s; v.w *= s;
        x4[idx] = v;
    }
}

// One wave per dst node: lane f accumulates x[src*64+f] over the node's CSR
// segment, scales by nrm[node], optional bias, one coalesced 256B row write.
__global__ __launch_bounds__(256) void gather_agg(const float* __restrict__ x,
        const int* __restrict__ srcs, const int* __restrict__ offs,
        const float* __restrict__ nrm, const float* __restrict__ bias,
        float* __restrict__ out, int n_nodes) {
    int wave = blockIdx.x * 4 + (threadIdx.x >> 6);
    int f = threadIdx.x & 63;
    if (wave >= n_nodes) return;
    int e  = offs[wave];
    int e1 = offs[wave + 1];
    float acc = 0.0f;
    for (; e + 4 <= e1; e += 4) {
        int sA = srcs[e], sB = srcs[e + 1], sC = srcs[e + 2], sD = srcs[e + 3];
        float a0 = x[(size_t)sA * 64 + f];
        float a1 = x[(size_t)sB * 64 + f];
        float a2 = x[(size_t)sC * 64 + f];
        float a3 = x[(size_t)sD * 64 + f];
        acc += a0; acc += a1; acc += a2; acc += a3;
    }
    for (; e < e1; ++e) acc += x[(size_t)srcs[e] * 64 + f];
    acc *= nrm[wave];
    if (bias) acc += bias[f];
    out[(size_t)wave * 64 + f] = acc;
}

// Per-node: h1 = relu(agg1@W1 + b1); y2 = (h1*norm_out)@W2
// agg1 is pre-scaled by norm_dst in gather_agg.
__global__ __launch_bounds__(256) void fused_gemm(
        const float* __restrict__ agg1, const float* __restrict__ norm_out,
        const float* __restrict__ W1, const float* __restrict__ b1,
        const float* __restrict__ W2, float* __restrict__ y2, int n_nodes) {
    __shared__ float W1s[64 * 128];
    __shared__ float W2s[128 * 64];
    __shared__ float b1s[128];
    __shared__ float tt[2][64];
    __shared__ float hs[2][128];

    for (int idx = threadIdx.x; idx < 64 * 128; idx += 256) {
        W1s[idx] = W1[idx];
        W2s[idx] = W2[idx];
    }
    if (threadIdx.x < 128) b1s[threadIdx.x] = b1[threadIdx.x];
    __syncthreads();

    const int g  = threadIdx.x >> 7;
    const int tj = threadIdx.x & 127;

    for (int i0 = blockIdx.x * 2; i0 < n_nodes; i0 += gridDim.x * 2) {
        int i = i0 + g;
        bool valid = (i < n_nodes);
        if (valid && tj < 64) tt[g][tj] = agg1[i * 64 + tj];
        __syncthreads();
        if (valid) {
            float acc = b1s[tj];
            #pragma unroll
            for (int k = 0; k < 64; ++k) acc += tt[g][k] * W1s[k * 128 + tj];
            acc = acc > 0.0f ? acc : 0.0f;
            hs[g][tj] = acc * norm_out[i];
        }
        __syncthreads();
        if (valid && tj < 64) {
            float acc = 0.0f;
            #pragma unroll
            for (int j = 0; j < 128; ++j) acc += hs[g][j] * W2s[j * 64 + tj];
            y2[i * 64 + tj] = acc;
        }
        __syncthreads();
    }
}

extern "C" void kernel_launch(void* const* d_in, const int* in_sizes, int n_in,
                              void* d_out, int out_size, void* d_ws, size_t ws_size,
                              hipStream_t stream) {
    const float* h   = (const float*)d_in[0];
    const int*   src = (const int*)d_in[1];
    const int*   dst = (const int*)d_in[2];
    const float* W1  = (const float*)d_in[3];
    const float* b1  = (const float*)d_in[4];
    const float* W2  = (const float*)d_in[5];
    const float* b2  = (const float*)d_in[6];
    float* out = (float*)d_out;

    const int n_nodes = in_sizes[0] / 64;
    const int n_edges = in_sizes[1];

    float* ws = (float*)d_ws;
    float* x        = ws;                           // [n,64]; reused as y2 later
    float* agg1     = x + (size_t)n_nodes * 64;     // [n,64]
    float* norm_src = agg1 + (size_t)n_nodes * 64;  // [n]
    float* norm_dst = norm_src + n_nodes;           // [n]
    int* cnt_out    = (int*)(norm_dst + n_nodes);   // [n]
    int* cnt_in     = cnt_out + n_nodes;            // [n]
    int* offs       = cnt_in + n_nodes;             // [n+1]
    int* cursor     = offs + n_nodes + 1;           // [n]
    int* src_sorted = cursor + n_nodes;             // [E]
    float* y2 = x;  // alias: x dead after first gather_agg

    hipMemsetAsync(cnt_out, 0, 2 * (size_t)n_nodes * sizeof(int), stream);

    int eb = (n_edges + 255) / 256;
    int nb = (n_nodes + 255) / 256;

    count_kernel<<<eb, 256, 0, stream>>>(src, dst, cnt_out, cnt_in, n_edges);
    norm_kernel<<<nb, 256, 0, stream>>>(cnt_out, cnt_in, norm_src, norm_dst, n_nodes);
    scan_kernel<<<1, 1024, 0, stream>>>(cnt_in, offs, cursor, n_nodes);
    place_kernel<<<eb, 256, 0, stream>>>(src, dst, cursor, src_sorted, n_edges);

    int n4 = n_nodes * 16;
    scale_kernel<<<(n4 + 255) / 256, 256, 0, stream>>>((const float4*)h, norm_src, (float4*)x, n4);

    int gb = (n_nodes + 3) / 4;
    gather_agg<<<gb, 256, 0, stream>>>(x, src_sorted, offs, norm_dst, nullptr, agg1, n_nodes);

    fused_gemm<<<1024, 256, 0, stream>>>(agg1, norm_src, W1, b1, W2, y2, n_nodes);

    gather_agg<<<gb, 256, 0, stream>>>(y2, src_sorted, offs, norm_dst, b2, out, n_nodes);
}

// Round 3
// 342.981 us; speedup vs baseline: 1.8345x; 1.2792x over previous
//
#include <hip/hip_runtime.h>

// F0=64, F1=128, F2=64.
// Pipeline: count -> norm -> scan(CSR) -> place -> scale -> gather1 ->
//           gemm1(relu+b1+norm fold) -> gemm2 -> gather2(+b2)

__global__ void count_kernel(const int* __restrict__ src, const int* __restrict__ dst,
                             int* __restrict__ cnt_out, int* __restrict__ cnt_in,
                             int n_edges) {
    int e = blockIdx.x * blockDim.x + threadIdx.x;
    if (e < n_edges) {
        atomicAdd(&cnt_out[src[e]], 1);
        atomicAdd(&cnt_in[dst[e]], 1);
    }
}

__global__ void norm_kernel(const int* __restrict__ cnt_out, const int* __restrict__ cnt_in,
                            float* __restrict__ norm_src, float* __restrict__ norm_dst, int n) {
    int i = blockIdx.x * blockDim.x + threadIdx.x;
    if (i < n) {
        int co = cnt_out[i]; if (co < 1) co = 1;
        int ci = cnt_in[i];  if (ci < 1) ci = 1;
        norm_src[i] = 1.0f / sqrtf((float)co);
        norm_dst[i] = 1.0f / sqrtf((float)ci);
    }
}

// Single-block exclusive scan of cnt[0..n) -> offs[0..n], copy to cursor.
__global__ __launch_bounds__(1024) void scan_kernel(const int* __restrict__ cnt,
                                                    int* __restrict__ offs,
                                                    int* __restrict__ cursor, int n) {
    __shared__ int wsum[16];
    const int lane = threadIdx.x & 63;
    const int wid  = threadIdx.x >> 6;
    int carry = 0;
    for (int base = 0; base < n; base += 1024) {
        int i = base + (int)threadIdx.x;
        int v = (i < n) ? cnt[i] : 0;
        int incl = v;
        #pragma unroll
        for (int d = 1; d < 64; d <<= 1) {
            int t = __shfl_up(incl, d, 64);
            if (lane >= d) incl += t;
        }
        if (lane == 63) wsum[wid] = incl;
        __syncthreads();
        if (wid == 0) {
            int w = (lane < 16) ? wsum[lane] : 0;
            #pragma unroll
            for (int d = 1; d < 16; d <<= 1) {
                int t = __shfl_up(w, d, 64);
                if (lane >= d) w += t;
            }
            if (lane < 16) wsum[lane] = w;
        }
        __syncthreads();
        int wexcl = (wid == 0) ? 0 : wsum[wid - 1];
        int excl = carry + wexcl + (incl - v);
        if (i < n) { offs[i] = excl; cursor[i] = excl; }
        int total = wsum[15];
        __syncthreads();
        carry += total;
    }
    if (threadIdx.x == 0) offs[n] = carry;
}

__global__ void place_kernel(const int* __restrict__ src, const int* __restrict__ dst,
                             int* __restrict__ cursor, int* __restrict__ src_sorted,
                             int n_edges) {
    int e = blockIdx.x * blockDim.x + threadIdx.x;
    if (e < n_edges) {
        int p = atomicAdd(&cursor[dst[e]], 1);
        src_sorted[p] = src[e];
    }
}

__global__ void scale_kernel(const float4* __restrict__ h4, const float* __restrict__ norm,
                             float4* __restrict__ x4, int n4) {
    int idx = blockIdx.x * blockDim.x + threadIdx.x;
    if (idx < n4) {
        float s = norm[idx >> 4];
        float4 v = h4[idx];
        v.x *= s; v.y *= s; v.z *= s; v.w *= s;
        x4[idx] = v;
    }
}

// One wave per dst node. 16 lanes x float4 cover the 64-float row; the 4
// lane-quarters process 4 edges concurrently (4x MLP per serial step).
// Cross-quarter reduce via shfl_xor(16,32); quarter 0 writes the row.
__global__ __launch_bounds__(256) void gather_agg(const float* __restrict__ x,
        const int* __restrict__ srcs, const int* __restrict__ offs,
        const float* __restrict__ nrm, const float* __restrict__ bias,
        float* __restrict__ out, int n_nodes) {
    int wave = blockIdx.x * 4 + (threadIdx.x >> 6);
    if (wave >= n_nodes) return;
    int lane = threadIdx.x & 63;
    int g  = lane >> 4;         // edge subgroup 0..3
    int c4 = (lane & 15) * 4;   // column offset
    int e0 = offs[wave];
    int e1 = offs[wave + 1];
    float ax = 0.0f, ay = 0.0f, az = 0.0f, aw = 0.0f;
    for (int base = e0; base < e1; base += 8) {
        #pragma unroll
        for (int u = 0; u < 2; ++u) {
            int ei = base + u * 4 + g;
            int idx = ei < e1 ? ei : e1 - 1;
            float msk = ei < e1 ? 1.0f : 0.0f;
            int s = srcs[idx];
            const float4 v = *(const float4*)(x + (size_t)s * 64 + c4);
            ax = fmaf(v.x, msk, ax);
            ay = fmaf(v.y, msk, ay);
            az = fmaf(v.z, msk, az);
            aw = fmaf(v.w, msk, aw);
        }
    }
    #pragma unroll
    for (int off = 16; off < 64; off <<= 1) {
        ax += __shfl_xor(ax, off, 64);
        ay += __shfl_xor(ay, off, 64);
        az += __shfl_xor(az, off, 64);
        aw += __shfl_xor(aw, off, 64);
    }
    if (g == 0) {
        float s = nrm[wave];
        float4 r;
        r.x = ax * s; r.y = ay * s; r.z = az * s; r.w = aw * s;
        if (bias) {
            const float4 b = *(const float4*)(bias + c4);
            r.x += b.x; r.y += b.y; r.z += b.z; r.w += b.w;
        }
        *(float4*)(out + (size_t)wave * 64 + c4) = r;
    }
}

// H1[n,128] = relu(A[n,64] @ W1[64,128] + b1) * norm[node]
// 64-node tile, 256 threads, 4 nodes x 8 cols per thread.
__global__ __launch_bounds__(256) void gemm1(const float* __restrict__ A,
        const float* __restrict__ W1, const float* __restrict__ b1,
        const float* __restrict__ norm, float* __restrict__ H1, int n_nodes) {
    __shared__ float Ws[64 * 128];   // [k][j]
    __shared__ float As[64 * 68];    // padded stride 68
    __shared__ float b1s[128];
    const int tid = threadIdx.x;
    for (int idx = tid; idx < 64 * 128; idx += 256) Ws[idx] = W1[idx];
    if (tid < 128) b1s[tid] = b1[tid];

    const int m0 = blockIdx.x * 64;
    const float4* Ag = (const float4*)(A + (size_t)m0 * 64);
    #pragma unroll
    for (int i = 0; i < 4; ++i) {
        int idx = tid + i * 256;          // float4 index in tile [0,1024)
        int m = idx >> 4;
        int k4 = (idx & 15) * 4;
        float4 v = make_float4(0.f, 0.f, 0.f, 0.f);
        if (m0 + m < n_nodes) v = Ag[idx];
        *(float4*)(As + m * 68 + k4) = v;
    }
    __syncthreads();

    const int tx = tid & 15;   // col group: cols tx*8..+7
    const int ty = tid >> 4;   // node group: nodes ty*4..+3
    float acc[4][8];
    #pragma unroll
    for (int i = 0; i < 4; ++i)
        #pragma unroll
        for (int j = 0; j < 8; ++j) acc[i][j] = 0.0f;

    const float* Ap = As + ty * 4 * 68;
    const float* Wp = Ws + tx * 8;
    for (int k = 0; k < 64; ++k) {
        float a0 = Ap[k];
        float a1 = Ap[68 + k];
        float a2 = Ap[136 + k];
        float a3 = Ap[204 + k];
        float w[8];
        #pragma unroll
        for (int j = 0; j < 8; ++j) w[j] = Wp[k * 128 + j];
        #pragma unroll
        for (int j = 0; j < 8; ++j) {
            acc[0][j] = fmaf(a0, w[j], acc[0][j]);
            acc[1][j] = fmaf(a1, w[j], acc[1][j]);
            acc[2][j] = fmaf(a2, w[j], acc[2][j]);
            acc[3][j] = fmaf(a3, w[j], acc[3][j]);
        }
    }

    #pragma unroll
    for (int i = 0; i < 4; ++i) {
        int node = m0 + ty * 4 + i;
        if (node < n_nodes) {
            float s = norm[node];
            float r[8];
            #pragma unroll
            for (int j = 0; j < 8; ++j) {
                float v = acc[i][j] + b1s[tx * 8 + j];
                v = v > 0.0f ? v : 0.0f;
                r[j] = v * s;
            }
            float* o = H1 + (size_t)node * 128 + tx * 8;
            *(float4*)(o)     = make_float4(r[0], r[1], r[2], r[3]);
            *(float4*)(o + 4) = make_float4(r[4], r[5], r[6], r[7]);
        }
    }
}

// Y2[n,64] = H1[n,128] @ W2[128,64]
// 64-node tile, 256 threads, 4 nodes x 4 cols per thread.
__global__ __launch_bounds__(256) void gemm2(const float* __restrict__ H1,
        const float* __restrict__ W2, float* __restrict__ Y2, int n_nodes) {
    __shared__ float Ws[128 * 64];   // [k][j]
    __shared__ float Hs[64 * 132];   // padded stride 132
    const int tid = threadIdx.x;
    for (int idx = tid; idx < 128 * 64; idx += 256) Ws[idx] = W2[idx];

    const int m0 = blockIdx.x * 64;
    const float4* Hg = (const float4*)(H1 + (size_t)m0 * 128);
    #pragma unroll
    for (int i = 0; i < 8; ++i) {
        int idx = tid + i * 256;          // float4 index in tile [0,2048)
        int m = idx >> 5;
        int k4 = (idx & 31) * 4;
        float4 v = make_float4(0.f, 0.f, 0.f, 0.f);
        if (m0 + m < n_nodes) v = Hg[idx];
        *(float4*)(Hs + m * 132 + k4) = v;
    }
    __syncthreads();

    const int tx = tid & 15;   // cols tx*4..+3
    const int ty = tid >> 4;   // nodes ty*4..+3
    float acc[4][4];
    #pragma unroll
    for (int i = 0; i < 4; ++i)
        #pragma unroll
        for (int j = 0; j < 4; ++j) acc[i][j] = 0.0f;

    const float* Ap = Hs + ty * 4 * 132;
    for (int k = 0; k < 128; ++k) {
        float a0 = Ap[k];
        float a1 = Ap[132 + k];
        float a2 = Ap[264 + k];
        float a3 = Ap[396 + k];
        const float4 w = *(const float4*)(Ws + k * 64 + tx * 4);
        acc[0][0] = fmaf(a0, w.x, acc[0][0]); acc[0][1] = fmaf(a0, w.y, acc[0][1]);
        acc[0][2] = fmaf(a0, w.z, acc[0][2]); acc[0][3] = fmaf(a0, w.w, acc[0][3]);
        acc[1][0] = fmaf(a1, w.x, acc[1][0]); acc[1][1] = fmaf(a1, w.y, acc[1][1]);
        acc[1][2] = fmaf(a1, w.z, acc[1][2]); acc[1][3] = fmaf(a1, w.w, acc[1][3]);
        acc[2][0] = fmaf(a2, w.x, acc[2][0]); acc[2][1] = fmaf(a2, w.y, acc[2][1]);
        acc[2][2] = fmaf(a2, w.z, acc[2][2]); acc[2][3] = fmaf(a2, w.w, acc[2][3]);
        acc[3][0] = fmaf(a3, w.x, acc[3][0]); acc[3][1] = fmaf(a3, w.y, acc[3][1]);
        acc[3][2] = fmaf(a3, w.z, acc[3][2]); acc[3][3] = fmaf(a3, w.w, acc[3][3]);
    }

    #pragma unroll
    for (int i = 0; i < 4; ++i) {
        int node = m0 + ty * 4 + i;
        if (node < n_nodes) {
            *(float4*)(Y2 + (size_t)node * 64 + tx * 4) =
                make_float4(acc[i][0], acc[i][1], acc[i][2], acc[i][3]);
        }
    }
}

extern "C" void kernel_launch(void* const* d_in, const int* in_sizes, int n_in,
                              void* d_out, int out_size, void* d_ws, size_t ws_size,
                              hipStream_t stream) {
    const float* h   = (const float*)d_in[0];
    const int*   src = (const int*)d_in[1];
    const int*   dst = (const int*)d_in[2];
    const float* W1  = (const float*)d_in[3];
    const float* b1  = (const float*)d_in[4];
    const float* W2  = (const float*)d_in[5];
    const float* b2  = (const float*)d_in[6];
    float* out = (float*)d_out;

    const int n_nodes = in_sizes[0] / 64;
    const int n_edges = in_sizes[1];

    float* ws = (float*)d_ws;
    float* x        = ws;                            // [n,64]; reused as y2
    float* agg1     = x + (size_t)n_nodes * 64;      // [n,64]
    float* H1       = agg1 + (size_t)n_nodes * 64;   // [n,128]
    float* norm_src = H1 + (size_t)n_nodes * 128;    // [n]
    float* norm_dst = norm_src + n_nodes;            // [n]
    int* cnt_out    = (int*)(norm_dst + n_nodes);    // [n]
    int* cnt_in     = cnt_out + n_nodes;             // [n]
    int* offs       = cnt_in + n_nodes;              // [n+1]
    int* cursor     = offs + n_nodes + 1;            // [n]
    int* src_sorted = cursor + n_nodes;              // [E]
    float* y2 = x;  // alias: x dead after gather1

    hipMemsetAsync(cnt_out, 0, 2 * (size_t)n_nodes * sizeof(int), stream);

    int eb = (n_edges + 255) / 256;
    int nb = (n_nodes + 255) / 256;
    int tb = (n_nodes + 63) / 64;

    count_kernel<<<eb, 256, 0, stream>>>(src, dst, cnt_out, cnt_in, n_edges);
    norm_kernel<<<nb, 256, 0, stream>>>(cnt_out, cnt_in, norm_src, norm_dst, n_nodes);
    scan_kernel<<<1, 1024, 0, stream>>>(cnt_in, offs, cursor, n_nodes);
    place_kernel<<<eb, 256, 0, stream>>>(src, dst, cursor, src_sorted, n_edges);

    int n4 = n_nodes * 16;
    scale_kernel<<<(n4 + 255) / 256, 256, 0, stream>>>((const float4*)h, norm_src, (float4*)x, n4);

    int gb = (n_nodes + 3) / 4;
    gather_agg<<<gb, 256, 0, stream>>>(x, src_sorted, offs, norm_dst, nullptr, agg1, n_nodes);

    gemm1<<<tb, 256, 0, stream>>>(agg1, W1, b1, norm_src, H1, n_nodes);
    gemm2<<<tb, 256, 0, stream>>>(H1, W2, y2, n_nodes);

    gather_agg<<<gb, 256, 0, stream>>>(y2, src_sorted, offs, norm_dst, b2, out, n_nodes);
}